// Round 2
// baseline (713.994 us; speedup 1.0000x reference)
//
#include <hip/hip_runtime.h>
#include <math.h>

#define B_   384
#define NEL  32
#define NUP  16
#define NION 8
#define D_   256
#define P_   32
#define H_   256
#define NDET 16
#define NB   14
#define NAO  112
#define NMO  64
#define NORB 32

__device__ __forceinline__ float tanh_f(float x) {
    x = fminf(15.f, fmaxf(-15.f, x));
    float e = __expf(2.f * x);
    return (e - 1.f) / (e + 1.f);
}

// ---------------------------------------------------------------- K0: scalars
__global__ void k0_scalars(const float* h_ion, const float* W_decay, const float* b_decay,
                           const float* decay_scale, float* inv_ls2) {
    int t = threadIdx.x;
    if (t < NION) {
        float v = 0.f;
        for (int d = 0; d < 64; ++d) v += h_ion[t * 64 + d] * W_decay[d];
        v += b_decay[0];
        float th = tanh_f(v);
        float r = th / decay_scale[0];   // 1/ls ; sign killed by square
        inv_ls2[t] = r * r;
    }
}

// --------------------------------------------- K1: pre = h_el @ W0[:256] + b0
__global__ __launch_bounds__(256) void k1_pre(const float* h_el,
                                              const float* W0el, const float* b0el,
                                              const float* W0ion, const float* b0ion,
                                              float* pre_el, float* pre_ion) {
    __shared__ float x[NEL * D_];   // 32 KB
    int b = blockIdx.x, sel = blockIdx.y, t = threadIdx.x;
    const float* W0 = sel ? W0ion : W0el;
    const float* b0 = sel ? b0ion : b0el;
    float* pre = sel ? pre_ion : pre_el;

    for (int idx = t; idx < NEL * D_; idx += 256) x[idx] = h_el[(size_t)b * NEL * D_ + idx];
    __syncthreads();

    float acc[NEL];
#pragma unroll
    for (int r = 0; r < NEL; ++r) acc[r] = 0.f;
    int h = t;
    for (int d = 0; d < D_; ++d) {
        float w = W0[d * H_ + h];
#pragma unroll
        for (int r = 0; r < NEL; ++r) acc[r] += x[r * D_ + d] * w;
    }
    float bb = b0[h];
#pragma unroll
    for (int r = 0; r < NEL; ++r) pre[((size_t)b * NEL + r) * H_ + h] = acc[r] + bb;
}

// --------------------- K2: pair MLPs -> shift -> decay -> dist_ei per (b, i)
__global__ __launch_bounds__(256) void k2_shift(
    const float* h_el_el, const float* h_el_ion,
    const float* diff_el_el, const float* dist_el_el,
    const float* diff_el_ion, const float* dist_el_ion,
    const float* W0el, const float* W1el, const float* W0ion, const float* W1ion,
    const float* pre_el, const float* pre_ion, const float* inv_ls2,
    float* dist_ei_out) {
    __shared__ float Wp[P_ * H_];     // 32 KB  pair-part weights (phase-reused)
    __shared__ float pre_s[H_];
    __shared__ float pv[NEL * P_];    // 4 KB   pair embeddings (phase-reused)
    __shared__ float wpart[4][3];
    __shared__ float sdir[2][3];      // s_el , s_ion
    __shared__ float dterm[NION];

    int b = blockIdx.x, i = blockIdx.y, t = threadIdx.x;
    int lane = t & 63, w = t >> 6;
    int bi = b * NEL + i;

    // ================= electron-electron phase =================
    for (int idx = t; idx < P_ * H_; idx += 256) Wp[idx] = W0el[D_ * H_ + idx];
    for (int idx = t; idx < H_; idx += 256) pre_s[idx] = pre_el[(size_t)bi * H_ + idx];
    for (int idx = t; idx < NEL * P_; idx += 256) pv[idx] = h_el_el[(size_t)bi * NEL * P_ + idx];
    __syncthreads();

    float w1q[4];
#pragma unroll
    for (int q = 0; q < 4; ++q) w1q[q] = W1el[lane + 64 * q];

    float sx = 0.f, sy = 0.f, sz = 0.f;
    for (int g = 0; g < 2; ++g) {
        int j0 = w * 8 + g * 4;
        float tt[4][4];
#pragma unroll
        for (int q = 0; q < 4; ++q) {
            float p0 = pre_s[lane + 64 * q];
#pragma unroll
            for (int jj = 0; jj < 4; ++jj) tt[q][jj] = p0;
        }
        for (int p = 0; p < P_; ++p) {
            float wv[4];
#pragma unroll
            for (int q = 0; q < 4; ++q) wv[q] = Wp[p * H_ + lane + 64 * q];
#pragma unroll
            for (int jj = 0; jj < 4; ++jj) {
                float pvv = pv[(j0 + jj) * P_ + p];
#pragma unroll
                for (int q = 0; q < 4; ++q) tt[q][jj] += pvv * wv[q];
            }
        }
#pragma unroll
        for (int jj = 0; jj < 4; ++jj) {
            int j = j0 + jj;
            float part = 0.f;
#pragma unroll
            for (int q = 0; q < 4; ++q) part += tanh_f(tt[q][jj]) * w1q[q];
#pragma unroll
            for (int m = 1; m < 64; m <<= 1) part += __shfl_xor(part, m, 64);
            float dist = dist_el_el[(size_t)bi * NEL + j];
            float wgt = part / (1.f + dist * dist * dist);
            sx += wgt * diff_el_el[((size_t)bi * NEL + j) * 3 + 0];
            sy += wgt * diff_el_el[((size_t)bi * NEL + j) * 3 + 1];
            sz += wgt * diff_el_el[((size_t)bi * NEL + j) * 3 + 2];
        }
    }
    if (lane == 0) { wpart[w][0] = sx; wpart[w][1] = sy; wpart[w][2] = sz; }
    __syncthreads();
    if (t < 3) sdir[0][t] = wpart[0][t] + wpart[1][t] + wpart[2][t] + wpart[3][t];
    __syncthreads();

    // ================= electron-ion phase =================
    for (int idx = t; idx < P_ * H_; idx += 256) Wp[idx] = W0ion[D_ * H_ + idx];
    for (int idx = t; idx < H_; idx += 256) pre_s[idx] = pre_ion[(size_t)bi * H_ + idx];
    for (int idx = t; idx < NION * P_; idx += 256) pv[idx] = h_el_ion[(size_t)bi * NION * P_ + idx];
    __syncthreads();

#pragma unroll
    for (int q = 0; q < 4; ++q) w1q[q] = W1ion[lane + 64 * q];

    sx = sy = sz = 0.f;
    {
        int j0 = w * 2;
        float tt[4][2];
#pragma unroll
        for (int q = 0; q < 4; ++q) {
            float p0 = pre_s[lane + 64 * q];
#pragma unroll
            for (int jj = 0; jj < 2; ++jj) tt[q][jj] = p0;
        }
        for (int p = 0; p < P_; ++p) {
            float wv[4];
#pragma unroll
            for (int q = 0; q < 4; ++q) wv[q] = Wp[p * H_ + lane + 64 * q];
#pragma unroll
            for (int jj = 0; jj < 2; ++jj) {
                float pvv = pv[(j0 + jj) * P_ + p];
#pragma unroll
                for (int q = 0; q < 4; ++q) tt[q][jj] += pvv * wv[q];
            }
        }
#pragma unroll
        for (int jj = 0; jj < 2; ++jj) {
            int j = j0 + jj;
            float part = 0.f;
#pragma unroll
            for (int q = 0; q < 4; ++q) part += tanh_f(tt[q][jj]) * w1q[q];
#pragma unroll
            for (int m = 1; m < 64; m <<= 1) part += __shfl_xor(part, m, 64);
            float dist = dist_el_ion[(size_t)bi * NION + j];
            float wgt = part / (1.f + dist * dist * dist);
            sx += wgt * diff_el_ion[((size_t)bi * NION + j) * 3 + 0];
            sy += wgt * diff_el_ion[((size_t)bi * NION + j) * 3 + 1];
            sz += wgt * diff_el_ion[((size_t)bi * NION + j) * 3 + 2];
        }
    }
    if (lane == 0) { wpart[w][0] = sx; wpart[w][1] = sy; wpart[w][2] = sz; }
    __syncthreads();
    if (t < 3) sdir[1][t] = wpart[0][t] + wpart[1][t] + wpart[2][t] + wpart[3][t];
    __syncthreads();

    // ================= decay, shift, dist_ei =================
    if (t < NION) {
        float dk = dist_el_ion[(size_t)bi * NION + t];
        dterm[t] = tanh_f(dk * dk * inv_ls2[t]);
    }
    __syncthreads();
    if (t < NION) {
        float decay = 1.f;
#pragma unroll
        for (int k = 0; k < NION; ++k) decay *= dterm[k];
        float shx = (sdir[0][0] + sdir[1][0]) * decay;
        float shy = (sdir[0][1] + sdir[1][1]) * decay;
        float shz = (sdir[0][2] + sdir[1][2]) * decay;
        float dx = diff_el_ion[((size_t)bi * NION + t) * 3 + 0] + shx;
        float dy = diff_el_ion[((size_t)bi * NION + t) * 3 + 1] + shy;
        float dz = diff_el_ion[((size_t)bi * NION + t) * 3 + 2] + shz;
        dist_ei_out[(size_t)bi * NION + t] = sqrtf(dx * dx + dy * dy + dz * dz);
    }
}

// -------- K3: AO->MO, backflow MLP, CI weights, gather, final m_up / m_dn
__global__ __launch_bounds__(256) void k3_orbitals(
    const float* h_el, const float* alpha, const float* coeff_up, const float* coeff_dn,
    const float* ci_weights, const int* idx_up, const int* idx_dn,
    const float* W0up, const float* b0up, const float* W1up, const float* b1up,
    const float* W0dn, const float* b0dn, const float* W1dn, const float* b1dn,
    const float* dist_ei, float* out) {
    __shared__ float al[NB];
    __shared__ float ao[NUP][NAO + 2];   // pad to 114 for bank spread
    __shared__ float mo[NUP][NMO];
    __shared__ float xx[NUP * D_];       // 16 KB
    __shared__ float h1[NUP * H_];       // 16 KB
    __shared__ int   idxs[NDET * NUP];
    __shared__ float ciw_s[NDET], sgn_s[NDET];

    int b = blockIdx.x, s = blockIdx.y, t = threadIdx.x;
    int ebase = s * NUP;
    const float* coeff = s ? coeff_dn : coeff_up;
    const float* W0 = s ? W0dn : W0up;
    const float* b0 = s ? b0dn : b0up;
    const float* W1 = s ? W1dn : W1up;
    const float* b1 = s ? b1dn : b1up;
    const int* idxp = s ? idx_dn : idx_up;

    if (t < NB) al[t] = alpha[t];
    idxs[t] = idxp[t];
    if (t < NDET) {
        float ci = ci_weights[t];
        ciw_s[t] = powf(fabsf(ci), 1.0f / 16.0f);
        sgn_s[t] = ci < 0.f ? -1.f : 1.f;
    }
    __syncthreads();

    // ---- AOs ----
    if (t < NUP * NION) {
        int e = t >> 3, k = t & 7;
        float dd = dist_ei[((size_t)b * NEL + ebase + e) * NION + k];
        float d2 = dd * dd;
        for (int n = 0; n < NB; ++n) ao[e][k * NB + n] = __expf(-d2 * al[n]);
    }
    __syncthreads();

    // ---- MOs: thread -> (e = t>>4, 4 mo cols) ----
    {
        int e = t >> 4, m0 = (t & 15) * 4;
        float a0 = 0, a1 = 0, a2 = 0, a3 = 0;
        for (int a = 0; a < NAO; ++a) {
            float v = ao[e][a];
            a0 += v * coeff[a * NMO + m0 + 0];
            a1 += v * coeff[a * NMO + m0 + 1];
            a2 += v * coeff[a * NMO + m0 + 2];
            a3 += v * coeff[a * NMO + m0 + 3];
        }
        mo[e][m0 + 0] = a0; mo[e][m0 + 1] = a1; mo[e][m0 + 2] = a2; mo[e][m0 + 3] = a3;
    }

    // ---- stage x for backflow MLP ----
    for (int idx = t; idx < NUP * D_; idx += 256) xx[idx] = h_el[((size_t)b * NEL + ebase) * D_ + idx];
    __syncthreads();

    // ---- phase 1: h1 = tanh(x @ W0 + b0) ----
    {
        int h = t;
        float acc[NUP];
#pragma unroll
        for (int r = 0; r < NUP; ++r) acc[r] = 0.f;
        for (int d = 0; d < D_; ++d) {
            float wv = W0[d * H_ + h];
#pragma unroll
            for (int r = 0; r < NUP; ++r) acc[r] += xx[r * D_ + d] * wv;
        }
        float bb = b0[h];
#pragma unroll
        for (int r = 0; r < NUP; ++r) h1[r * H_ + h] = tanh_f(acc[r] + bb);
    }
    __syncthreads();

    // ---- phase 2: y = h1 @ W1 + b1, gather, write ----
    {
        int c0 = t, c1 = t + 256;
        float acc0[NUP], acc1[NUP];
#pragma unroll
        for (int r = 0; r < NUP; ++r) { acc0[r] = 0.f; acc1[r] = 0.f; }
        for (int h = 0; h < H_; ++h) {
            float wa = W1[h * 512 + c0];
            float wb = W1[h * 512 + c1];
#pragma unroll
            for (int r = 0; r < NUP; ++r) {
                float hv = h1[r * H_ + h];
                acc0[r] += hv * wa;
                acc1[r] += hv * wb;
            }
        }
        float ba = b1[c0], bb2 = b1[c1];
        size_t outbase = (size_t)s * ((size_t)B_ * NDET * NUP * NORB);
        for (int cc = 0; cc < 2; ++cc) {
            int c = cc ? c1 : c0;
            float badd = cc ? bb2 : ba;
            int d = c >> 5, o = c & 31;
#pragma unroll
            for (int r = 0; r < NUP; ++r) {
                float y = (cc ? acc1[r] : acc0[r]) + badd;
                float selv;
                if (s == 0) {
                    selv = (o < NUP) ? mo[r][idxs[d * NUP + o]] * ciw_s[d] * (o == 0 ? sgn_s[d] : 1.f)
                                     : 0.f;
                } else {
                    selv = (o >= NUP) ? mo[r][idxs[d * NUP + (o - NUP)]] : 0.f;
                }
                out[outbase + (((size_t)b * NDET + d) * NUP + r) * NORB + o] = selv * y;
            }
        }
    }
}

// ------------------------------------------------------------------ launcher
extern "C" void kernel_launch(void* const* d_in, const int* in_sizes, int n_in,
                              void* d_out, int out_size, void* d_ws, size_t ws_size,
                              hipStream_t stream) {
    const float* h_el        = (const float*)d_in[0];
    const float* h_el_el     = (const float*)d_in[1];
    const float* h_el_ion    = (const float*)d_in[2];
    const float* h_ion       = (const float*)d_in[3];
    const float* diff_el_el  = (const float*)d_in[4];
    const float* dist_el_el  = (const float*)d_in[5];
    const float* diff_el_ion = (const float*)d_in[6];
    const float* dist_el_ion = (const float*)d_in[7];
    const float* W_shift_el0 = (const float*)d_in[8];
    const float* b_shift_el0 = (const float*)d_in[9];
    const float* W_shift_el1 = (const float*)d_in[10];
    const float* W_shift_ion0= (const float*)d_in[11];
    const float* b_shift_ion0= (const float*)d_in[12];
    const float* W_shift_ion1= (const float*)d_in[13];
    const float* decay_scale = (const float*)d_in[14];
    const float* W_decay     = (const float*)d_in[15];
    const float* b_decay     = (const float*)d_in[16];
    const float* alpha       = (const float*)d_in[17];
    const float* coeff_up    = (const float*)d_in[18];
    const float* coeff_dn    = (const float*)d_in[19];
    const float* ci_weights  = (const float*)d_in[20];
    const float* W_bf_up0    = (const float*)d_in[21];
    const float* b_bf_up0    = (const float*)d_in[22];
    const float* W_bf_up1    = (const float*)d_in[23];
    const float* b_bf_up1    = (const float*)d_in[24];
    const float* W_bf_dn0    = (const float*)d_in[25];
    const float* b_bf_dn0    = (const float*)d_in[26];
    const float* W_bf_dn1    = (const float*)d_in[27];
    const float* b_bf_dn1    = (const float*)d_in[28];
    const int*  idx_up       = (const int*)d_in[29];
    const int*  idx_dn       = (const int*)d_in[30];
    float* out = (float*)d_out;

    float* ws      = (float*)d_ws;
    float* inv_ls2 = ws;                                   // 8
    float* pre_el  = ws + 64;                              // B*32*256
    float* pre_ion = pre_el + (size_t)B_ * NEL * H_;       // B*32*256
    float* dist_ei = pre_ion + (size_t)B_ * NEL * H_;      // B*32*8

    k0_scalars<<<1, 64, 0, stream>>>(h_ion, W_decay, b_decay, decay_scale, inv_ls2);
    k1_pre<<<dim3(B_, 2), 256, 0, stream>>>(h_el, W_shift_el0, b_shift_el0,
                                            W_shift_ion0, b_shift_ion0, pre_el, pre_ion);
    k2_shift<<<dim3(B_, NEL), 256, 0, stream>>>(h_el_el, h_el_ion,
                                                diff_el_el, dist_el_el, diff_el_ion, dist_el_ion,
                                                W_shift_el0, W_shift_el1, W_shift_ion0, W_shift_ion1,
                                                pre_el, pre_ion, inv_ls2, dist_ei);
    k3_orbitals<<<dim3(B_, 2), 256, 0, stream>>>(h_el, alpha, coeff_up, coeff_dn,
                                                 ci_weights, idx_up, idx_dn,
                                                 W_bf_up0, b_bf_up0, W_bf_up1, b_bf_up1,
                                                 W_bf_dn0, b_bf_dn0, W_bf_dn1, b_bf_dn1,
                                                 dist_ei, out);
}

// Round 3
// 532.937 us; speedup vs baseline: 1.3397x; 1.3397x over previous
//
#include <hip/hip_runtime.h>
#include <math.h>

#define B_   384
#define NEL  32
#define NUP  16
#define NION 8
#define D_   256
#define P_   32
#define H_   256
#define NDET 16
#define NB   14
#define NAO  112
#define NMO  64
#define NORB 32
#define ITILE 4

typedef __attribute__((ext_vector_type(4))) float fv4;

__device__ __forceinline__ float tanh_f(float x) {
    x = fminf(15.f, fmaxf(-15.f, x));
    float e = __expf(2.f * x);
    return (e - 1.f) / (e + 1.f);
}

// ---------------------------------------------------------------- K0: scalars
__global__ void k0_scalars(const float* h_ion, const float* W_decay, const float* b_decay,
                           const float* decay_scale, float* inv_ls2) {
    int t = threadIdx.x;
    if (t < NION) {
        float v = 0.f;
        for (int d = 0; d < 64; ++d) v += h_ion[t * 64 + d] * W_decay[d];
        v += b_decay[0];
        float th = tanh_f(v);
        float r = th / decay_scale[0];   // 1/ls ; sign killed by square
        inv_ls2[t] = r * r;
    }
}

// --------------------------------------------- K1: pre = h_el @ W0[:256] + b0
// thread tile: 4 rows x 8 cols; W from global (L2-resident), x from LDS b32 broadcast
__global__ __launch_bounds__(256, 4) void k1_pre(const float* h_el,
                                                 const float* W0el, const float* b0el,
                                                 const float* W0ion, const float* b0ion,
                                                 float* pre_el, float* pre_ion) {
    __shared__ float x[NEL * D_];   // 32 KB
    int b = blockIdx.x, sel = blockIdx.y, t = threadIdx.x;
    const float* W0 = sel ? W0ion : W0el;
    const float* b0 = sel ? b0ion : b0el;
    float* pre = sel ? pre_ion : pre_el;

    for (int i4 = t * 4; i4 < NEL * D_; i4 += 1024)
        *(fv4*)&x[i4] = *(const fv4*)&h_el[(size_t)b * NEL * D_ + i4];
    __syncthreads();

    int hg = t & 31, rg = t >> 5;
    int h0 = hg * 8, r0 = rg * 4;
    fv4 acc[4][2];
#pragma unroll
    for (int rr = 0; rr < 4; ++rr) { acc[rr][0] = (fv4)0.f; acc[rr][1] = (fv4)0.f; }

#pragma unroll 4
    for (int d = 0; d < D_; ++d) {
        fv4 wA = *(const fv4*)&W0[d * H_ + h0];
        fv4 wB = *(const fv4*)&W0[d * H_ + h0 + 4];
#pragma unroll
        for (int rr = 0; rr < 4; ++rr) {
            float xv = x[(r0 + rr) * D_ + d];
            acc[rr][0] += xv * wA;
            acc[rr][1] += xv * wB;
        }
    }
    fv4 bA = *(const fv4*)&b0[h0];
    fv4 bB = *(const fv4*)&b0[h0 + 4];
#pragma unroll
    for (int rr = 0; rr < 4; ++rr) {
        size_t base = ((size_t)b * NEL + r0 + rr) * H_ + h0;
        *(fv4*)&pre[base]     = acc[rr][0] + bA;
        *(fv4*)&pre[base + 4] = acc[rr][1] + bB;
    }
}

// --------------------- K2: pair MLPs -> shift -> decay -> dist_ei, ITILE i per block
__global__ __launch_bounds__(256, 2) void k2_shift(
    const float* h_el_el, const float* h_el_ion,
    const float* diff_el_el, const float* dist_el_el,
    const float* diff_el_ion, const float* dist_el_ion,
    const float* W0el, const float* W1el, const float* W0ion, const float* W1ion,
    const float* pre_el, const float* pre_ion, const float* inv_ls2,
    float* dist_ei_out) {
    __shared__ float Wp[P_ * H_];            // 32 KB (el then ion)
    __shared__ float pvb[ITILE * 1024];      // 16 KB transposed pair embeddings
    __shared__ float pre4[ITILE][H_];        // 4 KB
    __shared__ float dde[ITILE][NEL][4];     // 2 KB  (dx,dy,dz,dist)
    __shared__ float ddi[ITILE][NION][4];    // 0.5 KB
    __shared__ float wpart[ITILE][4][3];
    __shared__ float sh_el[ITILE][3], sh_ion[ITILE][3];
    __shared__ float dts[ITILE][NION];

    int it = blockIdx.x, b = blockIdx.y, t = threadIdx.x;
    int lane = t & 63, w = t >> 6;
    int bi0 = b * NEL + it * ITILE;
    int h0 = lane * 4;

    // ================= stage A (el weights + all per-i el data) =================
    for (int i4 = t * 4; i4 < P_ * H_; i4 += 1024)
        *(fv4*)&Wp[i4] = *(const fv4*)&W0el[D_ * H_ + i4];
    {
        int p = t & 31, jq = t >> 5;                 // jq: 8 groups of 4 j
        for (int i = 0; i < ITILE; ++i) {
            const float* src = h_el_el + ((size_t)(bi0 + i) * NEL + jq * 4) * P_ + p;
            fv4 v; v[0] = src[0]; v[1] = src[P_]; v[2] = src[2 * P_]; v[3] = src[3 * P_];
            *(fv4*)&pvb[i * 1024 + p * 32 + ((jq ^ (p & 7)) << 2)] = v;
        }
    }
    for (int idx = t; idx < ITILE * H_; idx += 256)
        pre4[idx >> 8][idx & 255] = pre_el[(size_t)(bi0 + (idx >> 8)) * H_ + (idx & 255)];
    for (int idx = t; idx < ITILE * NEL * 4; idx += 256) {
        int i = idx >> 7, r = idx & 127, j = r >> 2, e = r & 3;
        dde[i][j][e] = (e < 3) ? diff_el_el[((size_t)(bi0 + i) * NEL + j) * 3 + e]
                               : dist_el_el[(size_t)(bi0 + i) * NEL + j];
    }
    if (t < ITILE * NION * 4) {
        int i = t >> 5, r = t & 31, k = r >> 2, e = r & 3;
        ddi[i][k][e] = (e < 3) ? diff_el_ion[((size_t)(bi0 + i) * NION + k) * 3 + e]
                               : dist_el_ion[(size_t)(bi0 + i) * NION + k];
    }
    __syncthreads();

    // ================= el-el phase: 8 j per wave, 4 h per lane =================
    {
        fv4 w1 = *(const fv4*)&W1el[h0];
        int jg0 = w * 2, jg1 = w * 2 + 1;
        for (int i = 0; i < ITILE; ++i) {
            int ioff = i * 1024;
            int baseA[8], baseB[8];
#pragma unroll
            for (int k = 0; k < 8; ++k) {
                baseA[k] = ioff + ((jg0 ^ k) << 2);
                baseB[k] = ioff + ((jg1 ^ k) << 2);
            }
            fv4 pre = *(const fv4*)&pre4[i][h0];
            fv4 tt[8];
#pragma unroll
            for (int jj = 0; jj < 8; ++jj) tt[jj] = pre;
#pragma unroll
            for (int p = 0; p < P_; ++p) {
                fv4 wv = *(const fv4*)&Wp[p * H_ + h0];
                fv4 pa = *(const fv4*)&pvb[baseA[p & 7] + p * 32];
                fv4 pb = *(const fv4*)&pvb[baseB[p & 7] + p * 32];
#pragma unroll
                for (int e = 0; e < 4; ++e) {
                    tt[e]     += pa[e] * wv;
                    tt[4 + e] += pb[e] * wv;
                }
            }
            float sx = 0.f, sy = 0.f, sz = 0.f;
#pragma unroll
            for (int jj = 0; jj < 8; ++jj) {
                int j = w * 8 + jj;
                float s = tanh_f(tt[jj][0]) * w1[0] + tanh_f(tt[jj][1]) * w1[1]
                        + tanh_f(tt[jj][2]) * w1[2] + tanh_f(tt[jj][3]) * w1[3];
#pragma unroll
                for (int m = 1; m < 64; m <<= 1) s += __shfl_xor(s, m, 64);
                fv4 dd = *(const fv4*)&dde[i][j][0];
                float wgt = s / (1.f + dd[3] * dd[3] * dd[3]);
                sx += wgt * dd[0]; sy += wgt * dd[1]; sz += wgt * dd[2];
            }
            if (lane == 0) { wpart[i][w][0] = sx; wpart[i][w][1] = sy; wpart[i][w][2] = sz; }
        }
    }
    __syncthreads();
    if (t < ITILE * 3) {
        int i = t / 3, d = t - i * 3;
        sh_el[i][d] = wpart[i][0][d] + wpart[i][1][d] + wpart[i][2][d] + wpart[i][3][d];
    }

    // ================= stage B (ion weights + per-i ion data) =================
    for (int i4 = t * 4; i4 < P_ * H_; i4 += 1024)
        *(fv4*)&Wp[i4] = *(const fv4*)&W0ion[D_ * H_ + i4];
    {
        int p = t >> 3, j = t & 7;
        for (int i = 0; i < ITILE; ++i)
            pvb[i * 256 + p * 8 + (((j >> 2) ^ (p & 1)) << 2) + (j & 3)] =
                h_el_ion[((size_t)(bi0 + i) * NION + j) * P_ + p];
    }
    for (int idx = t; idx < ITILE * H_; idx += 256)
        pre4[idx >> 8][idx & 255] = pre_ion[(size_t)(bi0 + (idx >> 8)) * H_ + (idx & 255)];
    __syncthreads();

    // ================= el-ion phase: 2 k per wave =================
    {
        fv4 w1 = *(const fv4*)&W1ion[h0];
        int jq = w >> 1, eb = (w & 1) * 2;
        for (int i = 0; i < ITILE; ++i) {
            int ioff = i * 256;
            fv4 pre = *(const fv4*)&pre4[i][h0];
            fv4 ta = pre, tb = pre;
#pragma unroll
            for (int p = 0; p < P_; ++p) {
                fv4 wv = *(const fv4*)&Wp[p * H_ + h0];
                const float* pp = &pvb[ioff + p * 8 + ((jq ^ (p & 1)) << 2) + eb];
                ta += pp[0] * wv;
                tb += pp[1] * wv;
            }
            float sx = 0.f, sy = 0.f, sz = 0.f;
#pragma unroll
            for (int jj = 0; jj < 2; ++jj) {
                fv4 tv = jj ? tb : ta;
                int k = w * 2 + jj;
                float s = tanh_f(tv[0]) * w1[0] + tanh_f(tv[1]) * w1[1]
                        + tanh_f(tv[2]) * w1[2] + tanh_f(tv[3]) * w1[3];
#pragma unroll
                for (int m = 1; m < 64; m <<= 1) s += __shfl_xor(s, m, 64);
                fv4 dd = *(const fv4*)&ddi[i][k][0];
                float wgt = s / (1.f + dd[3] * dd[3] * dd[3]);
                sx += wgt * dd[0]; sy += wgt * dd[1]; sz += wgt * dd[2];
            }
            if (lane == 0) { wpart[i][w][0] = sx; wpart[i][w][1] = sy; wpart[i][w][2] = sz; }
        }
    }
    __syncthreads();
    if (t < ITILE * 3) {
        int i = t / 3, d = t - i * 3;
        sh_ion[i][d] = wpart[i][0][d] + wpart[i][1][d] + wpart[i][2][d] + wpart[i][3][d];
    }
    if (t < ITILE * NION) {
        int i = t >> 3, k = t & 7;
        float dk = ddi[i][k][3];
        dts[i][k] = tanh_f(dk * dk * inv_ls2[k]);
    }
    __syncthreads();
    if (t < ITILE * NION) {
        int i = t >> 3, k = t & 7;
        float decay = 1.f;
#pragma unroll
        for (int kk = 0; kk < NION; ++kk) decay *= dts[i][kk];
        float shx = (sh_el[i][0] + sh_ion[i][0]) * decay;
        float shy = (sh_el[i][1] + sh_ion[i][1]) * decay;
        float shz = (sh_el[i][2] + sh_ion[i][2]) * decay;
        float dx = ddi[i][k][0] + shx;
        float dy = ddi[i][k][1] + shy;
        float dz = ddi[i][k][2] + shz;
        dist_ei_out[(size_t)(bi0 + i) * NION + k] = sqrtf(dx * dx + dy * dy + dz * dz);
    }
}

// -------- K3: AO->MO, backflow MLP, CI weights, gather, final m_up / m_dn
__global__ __launch_bounds__(256, 3) void k3_orbitals(
    const float* h_el, const float* alpha, const float* coeff_up, const float* coeff_dn,
    const float* ci_weights, const int* idx_up, const int* idx_dn,
    const float* W0up, const float* b0up, const float* W1up, const float* b1up,
    const float* W0dn, const float* b0dn, const float* W1dn, const float* b1dn,
    const float* dist_ei, float* out) {
    __shared__ float al[NB];
    __shared__ float ao[NUP][NAO + 2];
    __shared__ float mo[NUP][NMO];
    __shared__ float xx[NUP * D_];       // 16 KB
    __shared__ float h1[NUP * H_];       // 16 KB
    __shared__ int   idxs[NDET * NUP];
    __shared__ float ciw_s[NDET], sgn_s[NDET];

    int b = blockIdx.x, s = blockIdx.y, t = threadIdx.x;
    int ebase = s * NUP;
    const float* coeff = s ? coeff_dn : coeff_up;
    const float* W0 = s ? W0dn : W0up;
    const float* b0 = s ? b0dn : b0up;
    const float* W1 = s ? W1dn : W1up;
    const float* b1 = s ? b1dn : b1up;
    const int* idxp = s ? idx_dn : idx_up;

    if (t < NB) al[t] = alpha[t];
    idxs[t] = idxp[t];
    if (t < NDET) {
        float ci = ci_weights[t];
        ciw_s[t] = powf(fabsf(ci), 1.0f / 16.0f);
        sgn_s[t] = ci < 0.f ? -1.f : 1.f;
    }
    __syncthreads();

    // ---- AOs ----
    if (t < NUP * NION) {
        int e = t >> 3, k = t & 7;
        float dd = dist_ei[((size_t)b * NEL + ebase + e) * NION + k];
        float d2 = dd * dd;
        for (int n = 0; n < NB; ++n) ao[e][k * NB + n] = __expf(-d2 * al[n]);
    }
    __syncthreads();

    // ---- MOs: thread -> (e = t>>4, 4 mo cols), float4 coeff ----
    {
        int e = t >> 4, m0 = (t & 15) * 4;
        fv4 macc = (fv4)0.f;
        for (int a = 0; a < NAO; ++a)
            macc += ao[e][a] * *(const fv4*)&coeff[a * NMO + m0];
        *(fv4*)&mo[e][m0] = macc;
    }

    // ---- stage x ----
    for (int i4 = t * 4; i4 < NUP * D_; i4 += 1024)
        *(fv4*)&xx[i4] = *(const fv4*)&h_el[((size_t)b * NEL + ebase) * D_ + i4];
    __syncthreads();

    // ---- phase 1: h1 = tanh(x @ W0 + b0); tile 2r x 8h ----
    {
        int hg = t & 31, rg = t >> 5;
        int h0 = hg * 8, r0 = rg * 2;
        fv4 acc[2][2];
#pragma unroll
        for (int rr = 0; rr < 2; ++rr) { acc[rr][0] = (fv4)0.f; acc[rr][1] = (fv4)0.f; }
#pragma unroll 4
        for (int d = 0; d < D_; ++d) {
            fv4 wA = *(const fv4*)&W0[d * H_ + h0];
            fv4 wB = *(const fv4*)&W0[d * H_ + h0 + 4];
#pragma unroll
            for (int rr = 0; rr < 2; ++rr) {
                float xv = xx[(r0 + rr) * D_ + d];
                acc[rr][0] += xv * wA;
                acc[rr][1] += xv * wB;
            }
        }
        fv4 bA = *(const fv4*)&b0[h0];
        fv4 bB = *(const fv4*)&b0[h0 + 4];
#pragma unroll
        for (int rr = 0; rr < 2; ++rr) {
            fv4 vA = acc[rr][0] + bA, vB = acc[rr][1] + bB;
            fv4 oA, oB;
#pragma unroll
            for (int q = 0; q < 4; ++q) { oA[q] = tanh_f(vA[q]); oB[q] = tanh_f(vB[q]); }
            *(fv4*)&h1[(r0 + rr) * H_ + h0]     = oA;
            *(fv4*)&h1[(r0 + rr) * H_ + h0 + 4] = oB;
        }
    }
    __syncthreads();

    // ---- phase 2: y = h1 @ W1 + b1; tile 4r x 8c; gather & write ----
    {
        int cg = t & 63, rg = t >> 6;
        int c0 = cg * 8, r0 = rg * 4;
        fv4 acc[4][2];
#pragma unroll
        for (int rr = 0; rr < 4; ++rr) { acc[rr][0] = (fv4)0.f; acc[rr][1] = (fv4)0.f; }
#pragma unroll 2
        for (int h = 0; h < H_; ++h) {
            fv4 wA = *(const fv4*)&W1[h * 512 + c0];
            fv4 wB = *(const fv4*)&W1[h * 512 + c0 + 4];
#pragma unroll
            for (int rr = 0; rr < 4; ++rr) {
                float hv = h1[(r0 + rr) * H_ + h];
                acc[rr][0] += hv * wA;
                acc[rr][1] += hv * wB;
            }
        }
        fv4 bA = *(const fv4*)&b1[c0];
        fv4 bB = *(const fv4*)&b1[c0 + 4];
        int d = cg >> 2, o0 = (cg & 3) * 8;
        float ciw = ciw_s[d], sgn = sgn_s[d];
        size_t obase = (size_t)s * ((size_t)B_ * NDET * NUP * NORB)
                     + ((size_t)b * NDET + d) * NUP * NORB;
#pragma unroll
        for (int rr = 0; rr < 4; ++rr) {
            int r = r0 + rr;
            fv4 yA = acc[rr][0] + bA, yB = acc[rr][1] + bB;
            fv4 vA, vB;
#pragma unroll
            for (int oo = 0; oo < 8; ++oo) {
                int o = o0 + oo;
                float y = oo < 4 ? yA[oo] : yB[oo - 4];
                float selv;
                if (s == 0) {
                    selv = (o < NUP) ? mo[r][idxs[d * NUP + o]] * ciw * (o == 0 ? sgn : 1.f)
                                     : 0.f;
                } else {
                    selv = (o >= NUP) ? mo[r][idxs[d * NUP + (o - NUP)]] : 0.f;
                }
                float v = selv * y;
                if (oo < 4) vA[oo] = v; else vB[oo - 4] = v;
            }
            *(fv4*)&out[obase + (size_t)r * NORB + o0]     = vA;
            *(fv4*)&out[obase + (size_t)r * NORB + o0 + 4] = vB;
        }
    }
}

// ------------------------------------------------------------------ launcher
extern "C" void kernel_launch(void* const* d_in, const int* in_sizes, int n_in,
                              void* d_out, int out_size, void* d_ws, size_t ws_size,
                              hipStream_t stream) {
    const float* h_el        = (const float*)d_in[0];
    const float* h_el_el     = (const float*)d_in[1];
    const float* h_el_ion    = (const float*)d_in[2];
    const float* h_ion       = (const float*)d_in[3];
    const float* diff_el_el  = (const float*)d_in[4];
    const float* dist_el_el  = (const float*)d_in[5];
    const float* diff_el_ion = (const float*)d_in[6];
    const float* dist_el_ion = (const float*)d_in[7];
    const float* W_shift_el0 = (const float*)d_in[8];
    const float* b_shift_el0 = (const float*)d_in[9];
    const float* W_shift_el1 = (const float*)d_in[10];
    const float* W_shift_ion0= (const float*)d_in[11];
    const float* b_shift_ion0= (const float*)d_in[12];
    const float* W_shift_ion1= (const float*)d_in[13];
    const float* decay_scale = (const float*)d_in[14];
    const float* W_decay     = (const float*)d_in[15];
    const float* b_decay     = (const float*)d_in[16];
    const float* alpha       = (const float*)d_in[17];
    const float* coeff_up    = (const float*)d_in[18];
    const float* coeff_dn    = (const float*)d_in[19];
    const float* ci_weights  = (const float*)d_in[20];
    const float* W_bf_up0    = (const float*)d_in[21];
    const float* b_bf_up0    = (const float*)d_in[22];
    const float* W_bf_up1    = (const float*)d_in[23];
    const float* b_bf_up1    = (const float*)d_in[24];
    const float* W_bf_dn0    = (const float*)d_in[25];
    const float* b_bf_dn0    = (const float*)d_in[26];
    const float* W_bf_dn1    = (const float*)d_in[27];
    const float* b_bf_dn1    = (const float*)d_in[28];
    const int*  idx_up       = (const int*)d_in[29];
    const int*  idx_dn       = (const int*)d_in[30];
    float* out = (float*)d_out;

    float* ws      = (float*)d_ws;
    float* inv_ls2 = ws;                                   // 8
    float* pre_el  = ws + 64;                              // B*32*256
    float* pre_ion = pre_el + (size_t)B_ * NEL * H_;       // B*32*256
    float* dist_ei = pre_ion + (size_t)B_ * NEL * H_;      // B*32*8

    k0_scalars<<<1, 64, 0, stream>>>(h_ion, W_decay, b_decay, decay_scale, inv_ls2);
    k1_pre<<<dim3(B_, 2), 256, 0, stream>>>(h_el, W_shift_el0, b_shift_el0,
                                            W_shift_ion0, b_shift_ion0, pre_el, pre_ion);
    k2_shift<<<dim3(NEL / ITILE, B_), 256, 0, stream>>>(h_el_el, h_el_ion,
                                                diff_el_el, dist_el_el, diff_el_ion, dist_el_ion,
                                                W_shift_el0, W_shift_el1, W_shift_ion0, W_shift_ion1,
                                                pre_el, pre_ion, inv_ls2, dist_ei);
    k3_orbitals<<<dim3(B_, 2), 256, 0, stream>>>(h_el, alpha, coeff_up, coeff_dn,
                                                 ci_weights, idx_up, idx_dn,
                                                 W_bf_up0, b_bf_up0, W_bf_up1, b_bf_up1,
                                                 W_bf_dn0, b_bf_dn0, W_bf_dn1, b_bf_dn1,
                                                 dist_ei, out);
}